// Round 9
// baseline (626.292 us; speedup 1.0000x reference)
//
#include <hip/hip_runtime.h>
#include <hip/hip_bf16.h>
#include <math.h>

typedef __bf16 bf16;
typedef __bf16 bf16x2 __attribute__((ext_vector_type(2)));
typedef __bf16 bf16x4 __attribute__((ext_vector_type(4)));
typedef __bf16 bf16x8 __attribute__((ext_vector_type(8)));
typedef float f32x4 __attribute__((ext_vector_type(4)));

#define D_MODEL 2048
#define SEQ 2048
#define BATCH 4
#define NH 16
#define DK 128

typedef const __attribute__((address_space(1))) void* as1_ptr;
typedef __attribute__((address_space(3))) void* as3_ptr;

__device__ __forceinline__ void gld_lds16(const bf16* g, bf16* l) {
  __builtin_amdgcn_global_load_lds((as1_ptr)g, (as3_ptr)l, 16, 0, 0);
}

// native 2^x: single v_exp_f32 (R8 verified: attn VALUBusy 47->32%, -23 us).
extern "C" __device__ float __ocml_native_exp2_f32(float);
__device__ __forceinline__ float fast_exp2(float x) {
  return __ocml_native_exp2_f32(x);
}

// ---------------- fp32 -> bf16 conversion ----------------
__global__ void cvt_kernel(const float* __restrict__ in, bf16* __restrict__ out, int n8) {
  int i = blockIdx.x * 256 + threadIdx.x;
  if (i >= n8) return;
  long base = (long)i * 8;
  const float4* p = (const float4*)(in + base);
  float4 a = p[0], b = p[1];
  bf16x8 v;
  v[0] = (bf16)a.x; v[1] = (bf16)a.y; v[2] = (bf16)a.z; v[3] = (bf16)a.w;
  v[4] = (bf16)b.x; v[5] = (bf16)b.y; v[6] = (bf16)b.z; v[7] = (bf16)b.w;
  *(bf16x8*)(out + base) = v;
}

// 4 weight tensors in one dispatch (blockIdx.y selects)
__global__ void cvt4_kernel(const float* a, const float* b, const float* c, const float* d,
                            bf16* oa, bf16* ob, bf16* oc, bf16* od) {
  const float* in; bf16* out;
  switch (blockIdx.y) {
    case 0: in = a; out = oa; break;
    case 1: in = b; out = ob; break;
    case 2: in = c; out = oc; break;
    default: in = d; out = od; break;
  }
  int i = blockIdx.x * 256 + threadIdx.x;   // n8 = 524288, grid.x = 2048
  long base = (long)i * 8;
  const float4* p = (const float4*)(in + base);
  float4 x = p[0], y = p[1];
  bf16x8 v;
  v[0] = (bf16)x.x; v[1] = (bf16)x.y; v[2] = (bf16)x.z; v[3] = (bf16)x.w;
  v[4] = (bf16)y.x; v[5] = (bf16)y.y; v[6] = (bf16)y.z; v[7] = (bf16)y.w;
  *(bf16x8*)(out + base) = v;
}

// ---------------- GEMM: C[M,N] = A[M,K] * B[N,K]^T + bias ----------------
// 256x256 tile, BK=64, 8 waves (2Mx4N), 512 thr. R9: fine 4-phase interleave
// (m201/m196: the per-phase ds_read || G::load || MFMA interleave is the lever;
// coarse 2-phase was ~800 TF).
// Per K-tile: 4 phases, each = one C-quadrant x K=64 (16 MFMA):
//   ph1 (mh0,nh0): read Af(mh0)x8 + Bf0(nh0)x4; stage B(t+1)p0
//   ph2 (mh0,nh1): read Bf1(nh1)x4 [Af reused]; stage A(t+2)s0
//   ph3 (mh1,nh1): read Af(mh1)x8 [Bf1 reused]; stage B(t+2)p1
//   ph4 (mh1,nh0): read Bf0(nh0)x4 [Af reused]; stage A(t+2)s1
// Each phase: reads; stage; s_barrier; lgkmcnt(0)+sched_barrier; setprio(1);
// 16 MFMA; setprio(0); s_barrier.  Stages land in LDS slots proven dead: the
// lgkmcnt(0)-before-closing-barrier of the slot's last reader precedes every
// stage issue (WAR-safe).  Counted vmcnt(6) at tile top (3 half-units in
// flight across 8 barriers); vmcnt(0) only at the final tile.
// Staging sets: A s0 = rows {0-63,128-191} (both M-groups' mh0), s1 = rest;
// B p0 = rows {0-31,64-95,128-159,192-223} (all waves' nh0 cols), p1 = rest.
template<int OUT_F32, int BIAS_ROW>
__global__ __launch_bounds__(512, 2)
void gemm256(const bf16* __restrict__ A, const bf16* __restrict__ B,
             const float* __restrict__ bias, void* __restrict__ Cout, int K, int ldc)
{
  __shared__ alignas(16) bf16 As[2][256 * 64];
  __shared__ alignas(16) bf16 Bs[2][256 * 64];
  const int tid  = threadIdx.x;
  const int wave = tid >> 6, lane = tid & 63;
  const int quad = lane >> 4, l16 = lane & 15;
  const int n0 = blockIdx.x * 256, m0 = blockIdx.y * 256;
  const int wm = (wave >> 2) * 128, wn = (wave & 3) * 64;

  // stage pointers: unit (matrix, set, j): idx = wave*2+j in [0,16); 2 loads/thread/set.
  // group g covers tile rows g*8..g*8+7; LDS dest = buf + g*1024B (linear, lane*16).
  // global-side XOR pre-swizzle: LDS[r][slot s] = global 16B-chunk s^(r&7).
  const bf16 *ApS[2][2], *BpS[2][2];
  int gA[2][2], gB[2][2];
  for (int s = 0; s < 2; s++)
    for (int j = 0; j < 2; j++) {
      int idx = wave * 2 + j;
      int ga = (idx >> 3) * 16 + s * 8 + (idx & 7);     // A sets: 64-row granules
      int ra = ga * 8 + (lane >> 3);
      int ca = (lane & 7) ^ (ra & 7);
      ApS[s][j] = A + (long)(m0 + ra) * K + ca * 8; gA[s][j] = ga;
      int gb = (idx >> 2) * 8 + s * 4 + (idx & 3);      // B sets: 32-row granules
      int rb = gb * 8 + (lane >> 3);
      int cb = (lane & 7) ^ (rb & 7);
      BpS[s][j] = B + (long)(n0 + rb) * K + cb * 8; gB[s][j] = gb;
    }

#define STAGE_A(T2, S) { long k0_ = (long)(T2) * 64; int b_ = (T2) & 1; \
    for (int j = 0; j < 2; j++) gld_lds16(ApS[S][j] + k0_, &As[b_][gA[S][j] * 512]); }
#define STAGE_B(T2, S) { long k0_ = (long)(T2) * 64; int b_ = (T2) & 1; \
    for (int j = 0; j < 2; j++) gld_lds16(BpS[S][j] + k0_, &Bs[b_][gB[S][j] * 512]); }

#define READ_A(AF, MH) \
  for (int mi = 0; mi < 4; mi++) \
    for (int ks = 0; ks < 2; ks++) { \
      int ra_ = wm + ((MH) * 4 + mi) * 16 + l16; \
      int ch_ = (ks * 4 + quad) ^ (ra_ & 7); \
      AF[mi * 2 + ks] = *(const bf16x8*)(&Ab[ra_ * 64 + ch_ * 8]); \
    }
#define READ_B(BF, NHH) \
  for (int ni = 0; ni < 2; ni++) \
    for (int ks = 0; ks < 2; ks++) { \
      int rb_ = wn + ((NHH) * 2 + ni) * 16 + l16; \
      int ch_ = (ks * 4 + quad) ^ (rb_ & 7); \
      BF[ni * 2 + ks] = *(const bf16x8*)(&Bb[rb_ * 64 + ch_ * 8]); \
    }
#define MFMA16(AF, BF, MH, NHH) \
  for (int mi = 0; mi < 4; mi++) \
    for (int ni = 0; ni < 2; ni++) \
      for (int ks = 0; ks < 2; ks++) \
        acc[(MH) * 4 + mi][(NHH) * 2 + ni] = __builtin_amdgcn_mfma_f32_16x16x32_bf16( \
            AF[mi * 2 + ks], BF[ni * 2 + ks], acc[(MH) * 4 + mi][(NHH) * 2 + ni], 0, 0, 0);
#define PHASE_MFMA(AF, BF, MH, NHH) \
  __builtin_amdgcn_s_barrier(); \
  asm volatile("s_waitcnt lgkmcnt(0)" ::: "memory"); \
  __builtin_amdgcn_sched_barrier(0); \
  __builtin_amdgcn_s_setprio(1); \
  MFMA16(AF, BF, MH, NHH); \
  __builtin_amdgcn_s_setprio(0); \
  __builtin_amdgcn_s_barrier();

  f32x4 acc[8][4] = {};
  const int nt = K / 64;

  // prologue: steady-state issue order (unit = 2 loads):
  // [t=-2]: A0s0, B0p1, A0s1   [t=-1]: B0p0, A1s0, B1p1, A1s1
  STAGE_A(0, 0); STAGE_B(0, 1); STAGE_A(0, 1);
  STAGE_B(0, 0); STAGE_A(1, 0); STAGE_B(1, 1); STAGE_A(1, 1);

  for (int t = 0; t < nt; t++) {
    const int cur = t & 1;
    // everything older than the 3 newest units (6 loads) has landed ->
    // tile t's A s0/s1, B p0/p1 all resident after the barrier.
    if (t < nt - 1) { asm volatile("s_waitcnt vmcnt(6)" ::: "memory"); }
    else            { asm volatile("s_waitcnt vmcnt(0)" ::: "memory"); }
    __builtin_amdgcn_s_barrier();
    const bf16* Ab = As[cur];
    const bf16* Bb = Bs[cur];
    bf16x8 Af[8], Bf0[4], Bf1[4];

    // ph1 (mh0, nh0): A-s0 slot dies after this phase's reads
    READ_A(Af, 0); READ_B(Bf0, 0);
    if (t + 1 < nt) STAGE_B(t + 1, 0);        // B(t+1)p0 -> buf[t+1&1], slot dead since t-1 ph4
    PHASE_MFMA(Af, Bf0, 0, 0);

    // ph2 (mh0, nh1): Af reused; B-nh1 slot dies after this phase
    READ_B(Bf1, 1);
    if (t + 2 < nt) STAGE_A(t + 2, 0);        // A(t+2)s0 -> buf[cur], dead after ph1
    PHASE_MFMA(Af, Bf1, 0, 1);

    // ph3 (mh1, nh1): Bf1 reused; A-s1 slot dies after this phase
    READ_A(Af, 1);
    if (t + 2 < nt) STAGE_B(t + 2, 1);        // B(t+2)p1 -> buf[cur], dead after ph2
    PHASE_MFMA(Af, Bf1, 1, 1);

    // ph4 (mh1, nh0): B-nh0 re-read; dies at tile end
    READ_B(Bf0, 0);
    if (t + 2 < nt) STAGE_A(t + 2, 1);        // A(t+2)s1 -> buf[cur], dead after ph3
    PHASE_MFMA(Af, Bf0, 1, 0);
  }
  asm volatile("s_waitcnt vmcnt(0)" ::: "memory");

  // epilogue (layout unchanged from verified kernels)
  float bv[4];
  if (!BIAS_ROW)
    for (int ni = 0; ni < 4; ni++) bv[ni] = bias[n0 + wn + ni * 16 + l16];
  for (int mi = 0; mi < 8; mi++)
    for (int r = 0; r < 4; r++) {
      long row = m0 + wm + mi * 16 + quad * 4 + r;
      float bm = BIAS_ROW ? bias[row] : 0.0f;
      for (int ni = 0; ni < 4; ni++) {
        float v = acc[mi][ni][r] + (BIAS_ROW ? bm : bv[ni]);
        long idx = row * (long)ldc + n0 + wn + ni * 16 + l16;
        if (OUT_F32) ((float*)Cout)[idx] = v;
        else         ((bf16*)Cout)[idx] = (bf16)v;
      }
    }
#undef STAGE_A
#undef STAGE_B
#undef READ_A
#undef READ_B
#undef MFMA16
#undef PHASE_MFMA
}

// ---------------- RoPE tables: ctab[pos][j] = {cos, sin}, j=0..63 ----------------
__global__ void ropetab_kernel(float* __restrict__ ctab) {
  int idx = blockIdx.x * 256 + threadIdx.x;   // 131072
  int j = idx & 63, p = idx >> 6;
  float f = exp2f(-(float)j * 0.20762050593046f);  // log2(10000)/64
  float th = (float)p * f;
  ctab[idx * 2]     = cosf(th);
  ctab[idx * 2 + 1] = sinf(th);
}

// ---------------- RoPE (NeoX rotate-half), in-place, table-driven ----------------
__global__ void rope_kernel(bf16* __restrict__ Q, bf16* __restrict__ K,
                            const float* __restrict__ ctab) {
  long idx = (long)blockIdx.x * 256 + threadIdx.x;   // 4194304 per tensor
  bf16* P = blockIdx.y ? K : Q;
  int i2 = (int)(idx & 31);          // dim pair (2*i2, 2*i2+1)
  int h  = (int)((idx >> 5) & 15);
  long row = idx >> 9;               // 0..8191
  int pos = (int)(row & (SEQ - 1));
  float4 cs = *(const float4*)(ctab + ((long)pos * 64 + 2 * i2) * 2); // c0,s0,c1,s1
  long base = row * D_MODEL + h * DK + 2 * i2;
  bf16x2 x1 = *(bf16x2*)(P + base);
  bf16x2 x2 = *(bf16x2*)(P + base + 64);
  bf16x2 y1, y2;
  y1[0] = (bf16)((float)x1[0] * cs.x - (float)x2[0] * cs.y);
  y2[0] = (bf16)((float)x2[0] * cs.x + (float)x1[0] * cs.y);
  y1[1] = (bf16)((float)x1[1] * cs.z - (float)x2[1] * cs.w);
  y2[1] = (bf16)((float)x2[1] * cs.z + (float)x1[1] * cs.w);
  *(bf16x2*)(P + base)      = y1;
  *(bf16x2*)(P + base + 64) = y2;
}

// ---------------- attention: O = softmax(Q K^T / sqrt(dk)) V ----------------
// (identical to R8: QBLK=128 / 4 waves / dbuf KVBLK=64 / s-halved Ps / native exp2.
// R8 measured: 177 us, MfmaUtil 34%, VALUBusy 32%.)
__global__ __launch_bounds__(256, 2)
void attn_kernel(const bf16* __restrict__ Q, const bf16* __restrict__ K,
                 const bf16* __restrict__ Vt, bf16* __restrict__ O)
{
  __shared__ alignas(16) bf16 Ks[2][64 * 128];   // [s][d] swizzled, 2 x 16 KB
  __shared__ alignas(16) bf16 Vts[2][128 * 64];  // [d][s] swizzled, 2 x 16 KB
  __shared__ alignas(16) bf16 Ps[128 * 36];      // half of P^T [q][s'=32 +pad4]
  const int tid  = threadIdx.x;
  const int wave = tid >> 6, lane = tid & 63;
  const int quad = lane >> 4, l16 = lane & 15;
  const int qt = blockIdx.x, bh = blockIdx.y;
  const int b = bh >> 4, h = bh & 15;
  const long qrow0 = (long)b * SEQ + qt * 128;
  const bf16* Qb = Q + qrow0 * D_MODEL + h * DK;
  const bf16* Kb = K + (long)b * SEQ * D_MODEL + h * DK;
  const bf16* Vb = Vt + (long)(h * DK) * (BATCH * SEQ) + b * SEQ;  // ld = 8192

  bf16x8 Qf[2][4];
  for (int ni = 0; ni < 2; ni++)
    for (int ks = 0; ks < 4; ks++)
      Qf[ni][ks] = *(const bf16x8*)(Qb + (long)(wave * 32 + ni * 16 + l16) * D_MODEL + ks * 32 + quad * 8);

  const bf16* Ksrc[4]; const bf16* Vsrc[4];
  for (int i = 0; i < 4; i++) {
    int g = wave * 4 + i;
    int rk = 4 * g + (lane >> 4);                 // K tile row 0..63
    int ck = l16 ^ (rk & 7);
    Ksrc[i] = Kb + (long)rk * D_MODEL + ck * 8;
    int rv = 8 * g + (lane >> 3);                 // V tile row 0..127
    int cv = (lane & 7) ^ (rv & 7);
    Vsrc[i] = Vb + (long)rv * (BATCH * SEQ) + cv * 8;
  }

  f32x4 Oacc[8][2] = {};
  float lsum[2] = {0.0f, 0.0f};
  const float kSc = 0.088388347648318447f * 1.4426950408889634f; // (1/sqrt(128))*log2(e)
  const int swz = l16 & 7;

  for (int i = 0; i < 4; i++) gld_lds16(Ksrc[i], &Ks[0][(wave * 4 + i) * 512]);
  for (int i = 0; i < 4; i++) gld_lds16(Vsrc[i], &Vts[0][(wave * 4 + i) * 512]);
  __syncthreads();

  int cur = 0;
  for (int kt = 64; kt <= SEQ; kt += 64) {
    if (kt < SEQ) {
      for (int i = 0; i < 4; i++)
        gld_lds16(Ksrc[i] + (long)kt * D_MODEL, &Ks[cur ^ 1][(wave * 4 + i) * 512]);
      for (int i = 0; i < 4; i++)
        gld_lds16(Vsrc[i] + kt, &Vts[cur ^ 1][(wave * 4 + i) * 512]);
    }
    const bf16* Ksb = Ks[cur];
    const bf16* Vsb = Vts[cur];

    for (int hh = 0; hh < 2; hh++) {
      f32x4 Sc[2][2] = {};
      __builtin_amdgcn_s_setprio(1);
      for (int ks = 0; ks < 4; ks++) {
        bf16x8 Kf[2];
        for (int j = 0; j < 2; j++) {
          int si = hh * 2 + j;
          int c = (ks * 4 + quad) ^ swz;
          Kf[j] = *(const bf16x8*)(&Ksb[(si * 16 + l16) * 128 + c * 8]);
        }
        for (int j = 0; j < 2; j++)
          for (int ni = 0; ni < 2; ni++)
            Sc[j][ni] = __builtin_amdgcn_mfma_f32_16x16x32_bf16(Kf[j], Qf[ni][ks], Sc[j][ni], 0, 0, 0);
      }
      __builtin_amdgcn_s_setprio(0);

      for (int j = 0; j < 2; j++)
        for (int ni = 0; ni < 2; ni++) {
          bf16x4 pk;
          for (int r = 0; r < 4; r++) {
            float p = fast_exp2(Sc[j][ni][r] * kSc);
            lsum[ni] += p;
            pk[r] = (bf16)p;
          }
          *(bf16x4*)(&Ps[(wave * 32 + ni * 16 + l16) * 36 + j * 16 + quad * 4]) = pk;
        }

      __builtin_amdgcn_s_setprio(1);
      bf16x8 Pf[2];
      for (int ni = 0; ni < 2; ni++)
        Pf[ni] = *(const bf16x8*)(&Ps[(wave * 32 + ni * 16 + l16) * 36 + quad * 8]);
      for (int mi = 0; mi < 8; mi++) {
        int c = (hh * 4 + quad) ^ swz;
        bf16x8 Vf = *(const bf16x8*)(&Vsb[(mi * 16 + l16) * 64 + c * 8]);
        for (int ni = 0; ni < 2; ni++)
          Oacc[mi][ni] = __builtin_amdgcn_mfma_f32_16x16x32_bf16(Vf, Pf[ni], Oacc[mi][ni], 0, 0, 0);
      }
      __builtin_amdgcn_s_setprio(0);
    }

    __syncthreads();
    cur ^= 1;
  }

  for (int ni = 0; ni < 2; ni++) {
    lsum[ni] += __shfl_xor(lsum[ni], 16);
    lsum[ni] += __shfl_xor(lsum[ni], 32);
  }

  for (int ni = 0; ni < 2; ni++) {
    float rinv = 1.0f / lsum[ni];
    long rowbase = (qrow0 + wave * 32 + ni * 16 + l16) * (long)D_MODEL + h * DK + quad * 4;
    for (int mi = 0; mi < 8; mi++) {
      bf16x4 o;
      for (int r = 0; r < 4; r++) o[r] = (bf16)(Oacc[mi][ni][r] * rinv);
      *(bf16x4*)(O + rowbase + mi * 16) = o;
    }
  }
}

// ---------------- host ----------------
extern "C" void kernel_launch(void* const* d_in, const int* in_sizes, int n_in,
                              void* d_out, int out_size, void* d_ws, size_t ws_size,
                              hipStream_t stream) {
  const float* x  = (const float*)d_in[0];
  const float* Wq = (const float*)d_in[1];
  const float* bq = (const float*)d_in[2];
  const float* Wk = (const float*)d_in[3];
  const float* bk = (const float*)d_in[4];
  const float* Wv = (const float*)d_in[5];
  const float* bv = (const float*)d_in[6];
  const float* Wo = (const float*)d_in[7];
  const float* bo = (const float*)d_in[8];
  float* out = (float*)d_out;

  bf16* ws = (bf16*)d_ws;
  // bf16 element offsets; total 160 MB.
  bf16* xb  = ws;                    // 16777216 elems (dead after VtF gemm)
  bf16* Wqb = ws + 16777216;         //  4194304 each
  bf16* Wkb = ws + 20971520;
  bf16* Wvb = ws + 25165824;
  bf16* Wob = ws + 29360128;
  bf16* Qp  = ws + 33554432;         // 16777216
  bf16* Kp  = ws + 50331648;
  bf16* VtF = ws + 67108864;         // V^T: [2048 d^][8192 b*s]
  float* ctab = (float*)ws;          // 1 MB, alive only between VtF gemm and attn
  bf16* O   = xb;                    // attention output overlays xb (and ctab) after rope

  cvt_kernel<<<8192, 256, 0, stream>>>(x, xb, 2097152);
  cvt4_kernel<<<dim3(2048, 4), 256, 0, stream>>>(Wq, Wk, Wv, Wo, Wqb, Wkb, Wvb, Wob);

  // 256^2 tiles: grid = (N/256, M/256)
  gemm256<0, 0><<<dim3(8, 32), 512, 0, stream>>>(xb, Wqb, bq, Qp, 2048, 2048);
  gemm256<0, 0><<<dim3(8, 32), 512, 0, stream>>>(xb, Wkb, bk, Kp, 2048, 2048);
  // V^T = Wv · x^T : M=2048 (d^, row-bias bv), N=8192, ldc=8192
  gemm256<0, 1><<<dim3(32, 8), 512, 0, stream>>>(Wvb, xb, bv, VtF, 2048, 8192);

  ropetab_kernel<<<512, 256, 0, stream>>>(ctab);
  rope_kernel<<<dim3(16384, 2), 256, 0, stream>>>(Qp, Kp, ctab);

  attn_kernel<<<dim3(16, 64), 256, 0, stream>>>(Qp, Kp, VtF, O);

  gemm256<1, 0><<<dim3(8, 32), 512, 0, stream>>>(O, Wob, bo, out, 2048, 2048);
}

// Round 10
// 597.878 us; speedup vs baseline: 1.0475x; 1.0475x over previous
//
#include <hip/hip_runtime.h>
#include <hip/hip_bf16.h>
#include <math.h>

typedef __bf16 bf16;
typedef __bf16 bf16x2 __attribute__((ext_vector_type(2)));
typedef __bf16 bf16x4 __attribute__((ext_vector_type(4)));
typedef __bf16 bf16x8 __attribute__((ext_vector_type(8)));
typedef float f32x4 __attribute__((ext_vector_type(4)));

#define D_MODEL 2048
#define SEQ 2048
#define BATCH 4
#define NH 16
#define DK 128

typedef const __attribute__((address_space(1))) void* as1_ptr;
typedef __attribute__((address_space(3))) void* as3_ptr;

__device__ __forceinline__ void gld_lds16(const bf16* g, bf16* l) {
  __builtin_amdgcn_global_load_lds((as1_ptr)g, (as3_ptr)l, 16, 0, 0);
}

// native 2^x: single v_exp_f32 (R8 verified: attn VALUBusy 47->32%, -23 us).
extern "C" __device__ float __ocml_native_exp2_f32(float);
__device__ __forceinline__ float fast_exp2(float x) {
  return __ocml_native_exp2_f32(x);
}

// ---------------- fp32 -> bf16 conversion ----------------
__global__ void cvt_kernel(const float* __restrict__ in, bf16* __restrict__ out, int n8) {
  int i = blockIdx.x * 256 + threadIdx.x;
  if (i >= n8) return;
  long base = (long)i * 8;
  const float4* p = (const float4*)(in + base);
  float4 a = p[0], b = p[1];
  bf16x8 v;
  v[0] = (bf16)a.x; v[1] = (bf16)a.y; v[2] = (bf16)a.z; v[3] = (bf16)a.w;
  v[4] = (bf16)b.x; v[5] = (bf16)b.y; v[6] = (bf16)b.z; v[7] = (bf16)b.w;
  *(bf16x8*)(out + base) = v;
}

// 4 weight tensors in one dispatch (blockIdx.y selects)
__global__ void cvt4_kernel(const float* a, const float* b, const float* c, const float* d,
                            bf16* oa, bf16* ob, bf16* oc, bf16* od) {
  const float* in; bf16* out;
  switch (blockIdx.y) {
    case 0: in = a; out = oa; break;
    case 1: in = b; out = ob; break;
    case 2: in = c; out = oc; break;
    default: in = d; out = od; break;
  }
  int i = blockIdx.x * 256 + threadIdx.x;   // n8 = 524288, grid.x = 2048
  long base = (long)i * 8;
  const float4* p = (const float4*)(in + base);
  float4 x = p[0], y = p[1];
  bf16x8 v;
  v[0] = (bf16)x.x; v[1] = (bf16)x.y; v[2] = (bf16)x.z; v[3] = (bf16)x.w;
  v[4] = (bf16)y.x; v[5] = (bf16)y.y; v[6] = (bf16)y.z; v[7] = (bf16)y.w;
  *(bf16x8*)(out + base) = v;
}

// ---------------- GEMM: C[M,N] = A[M,K] * B[N,K]^T + bias ----------------
// 256x256 tile, BK=64, 8 waves (2Mx4N), 512 thr, fine 4-phase counted-vmcnt
// schedule (R9; perf == coarse R5 -> schedule-invariant wall).
// R10: + T1 XCD-chunked blockIdx swizzle. Default bid%8 assignment gives each
// XCD one N-column: 32 concurrent blocks stream ALL 32 A-panels (32 MB)
// through each XCD's 4 MB L2 -> ~270 MB L3->L2 per dispatch (~3 TB/s, the
// schedule-invariant wall). Chunked 8x4-tile chunks per XCD: concurrent
// k-slices (A 128KB + B 256KB) L2-resident -> A fetched once per chunk;
// L3 traffic ~100 MB. Bijective (256 blocks % 8 == 0).
template<int OUT_F32, int BIAS_ROW>
__global__ __launch_bounds__(512, 2)
void gemm256(const bf16* __restrict__ A, const bf16* __restrict__ B,
             const float* __restrict__ bias, void* __restrict__ Cout, int K, int ldc)
{
  __shared__ alignas(16) bf16 As[2][256 * 64];
  __shared__ alignas(16) bf16 Bs[2][256 * 64];
  const int tid  = threadIdx.x;
  const int wave = tid >> 6, lane = tid & 63;
  const int quad = lane >> 4, l16 = lane & 15;

  // T1 chunked swizzle: XCD = bid&7 owns a cw x (32/cw) tile chunk.
  const int nbx = gridDim.x;
  const int bid = blockIdx.y * nbx + blockIdx.x;
  const int xcd = bid & 7, slot = bid >> 3;
  const int cw  = (nbx >= 8) ? 8 : nbx;        // chunk width (x)
  const int chx = nbx / cw;                    // chunks along x
  const int bx  = (xcd % chx) * cw + (slot % cw);
  const int by  = (xcd / chx) * (32 / cw) + (slot / cw);
  const int n0 = bx * 256, m0 = by * 256;
  const int wm = (wave >> 2) * 128, wn = (wave & 3) * 64;

  // stage pointers: unit (matrix, set, j): idx = wave*2+j in [0,16); 2 loads/thread/set.
  // group g covers tile rows g*8..g*8+7; LDS dest = buf + g*1024B (linear, lane*16).
  // global-side XOR pre-swizzle: LDS[r][slot s] = global 16B-chunk s^(r&7).
  const bf16 *ApS[2][2], *BpS[2][2];
  int gA[2][2], gB[2][2];
  for (int s = 0; s < 2; s++)
    for (int j = 0; j < 2; j++) {
      int idx = wave * 2 + j;
      int ga = (idx >> 3) * 16 + s * 8 + (idx & 7);     // A sets: 64-row granules
      int ra = ga * 8 + (lane >> 3);
      int ca = (lane & 7) ^ (ra & 7);
      ApS[s][j] = A + (long)(m0 + ra) * K + ca * 8; gA[s][j] = ga;
      int gb = (idx >> 2) * 8 + s * 4 + (idx & 3);      // B sets: 32-row granules
      int rb = gb * 8 + (lane >> 3);
      int cb = (lane & 7) ^ (rb & 7);
      BpS[s][j] = B + (long)(n0 + rb) * K + cb * 8; gB[s][j] = gb;
    }

#define STAGE_A(T2, S) { long k0_ = (long)(T2) * 64; int b_ = (T2) & 1; \
    for (int j = 0; j < 2; j++) gld_lds16(ApS[S][j] + k0_, &As[b_][gA[S][j] * 512]); }
#define STAGE_B(T2, S) { long k0_ = (long)(T2) * 64; int b_ = (T2) & 1; \
    for (int j = 0; j < 2; j++) gld_lds16(BpS[S][j] + k0_, &Bs[b_][gB[S][j] * 512]); }

#define READ_A(AF, MH) \
  for (int mi = 0; mi < 4; mi++) \
    for (int ks = 0; ks < 2; ks++) { \
      int ra_ = wm + ((MH) * 4 + mi) * 16 + l16; \
      int ch_ = (ks * 4 + quad) ^ (ra_ & 7); \
      AF[mi * 2 + ks] = *(const bf16x8*)(&Ab[ra_ * 64 + ch_ * 8]); \
    }
#define READ_B(BF, NHH) \
  for (int ni = 0; ni < 2; ni++) \
    for (int ks = 0; ks < 2; ks++) { \
      int rb_ = wn + ((NHH) * 2 + ni) * 16 + l16; \
      int ch_ = (ks * 4 + quad) ^ (rb_ & 7); \
      BF[ni * 2 + ks] = *(const bf16x8*)(&Bb[rb_ * 64 + ch_ * 8]); \
    }
#define MFMA16(AF, BF, MH, NHH) \
  for (int mi = 0; mi < 4; mi++) \
    for (int ni = 0; ni < 2; ni++) \
      for (int ks = 0; ks < 2; ks++) \
        acc[(MH) * 4 + mi][(NHH) * 2 + ni] = __builtin_amdgcn_mfma_f32_16x16x32_bf16( \
            AF[mi * 2 + ks], BF[ni * 2 + ks], acc[(MH) * 4 + mi][(NHH) * 2 + ni], 0, 0, 0);
#define PHASE_MFMA(AF, BF, MH, NHH) \
  __builtin_amdgcn_s_barrier(); \
  asm volatile("s_waitcnt lgkmcnt(0)" ::: "memory"); \
  __builtin_amdgcn_sched_barrier(0); \
  __builtin_amdgcn_s_setprio(1); \
  MFMA16(AF, BF, MH, NHH); \
  __builtin_amdgcn_s_setprio(0); \
  __builtin_amdgcn_s_barrier();

  f32x4 acc[8][4] = {};
  const int nt = K / 64;

  // prologue: steady-state issue order (unit = 2 loads):
  // [t=-2]: A0s0, B0p1, A0s1   [t=-1]: B0p0, A1s0, B1p1, A1s1
  STAGE_A(0, 0); STAGE_B(0, 1); STAGE_A(0, 1);
  STAGE_B(0, 0); STAGE_A(1, 0); STAGE_B(1, 1); STAGE_A(1, 1);

  for (int t = 0; t < nt; t++) {
    const int cur = t & 1;
    // everything older than the 3 newest units (6 loads) has landed ->
    // tile t's A s0/s1, B p0/p1 all resident after the barrier.
    if (t < nt - 1) { asm volatile("s_waitcnt vmcnt(6)" ::: "memory"); }
    else            { asm volatile("s_waitcnt vmcnt(0)" ::: "memory"); }
    __builtin_amdgcn_s_barrier();
    const bf16* Ab = As[cur];
    const bf16* Bb = Bs[cur];
    bf16x8 Af[8], Bf0[4], Bf1[4];

    // ph1 (mh0, nh0): A-s0 slot dies after this phase's reads
    READ_A(Af, 0); READ_B(Bf0, 0);
    if (t + 1 < nt) STAGE_B(t + 1, 0);        // B(t+1)p0 -> buf[t+1&1], slot dead since t-1 ph4
    PHASE_MFMA(Af, Bf0, 0, 0);

    // ph2 (mh0, nh1): Af reused; B-nh1 slot dies after this phase
    READ_B(Bf1, 1);
    if (t + 2 < nt) STAGE_A(t + 2, 0);        // A(t+2)s0 -> buf[cur], dead after ph1
    PHASE_MFMA(Af, Bf1, 0, 1);

    // ph3 (mh1, nh1): Bf1 reused; A-s1 slot dies after this phase
    READ_A(Af, 1);
    if (t + 2 < nt) STAGE_B(t + 2, 1);        // B(t+2)p1 -> buf[cur], dead after ph2
    PHASE_MFMA(Af, Bf1, 1, 1);

    // ph4 (mh1, nh0): B-nh0 re-read; dies at tile end
    READ_B(Bf0, 0);
    if (t + 2 < nt) STAGE_A(t + 2, 1);        // A(t+2)s1 -> buf[cur], dead after ph3
    PHASE_MFMA(Af, Bf0, 1, 0);
  }
  asm volatile("s_waitcnt vmcnt(0)" ::: "memory");

  // epilogue (layout unchanged from verified kernels)
  float bv[4];
  if (!BIAS_ROW)
    for (int ni = 0; ni < 4; ni++) bv[ni] = bias[n0 + wn + ni * 16 + l16];
  for (int mi = 0; mi < 8; mi++)
    for (int r = 0; r < 4; r++) {
      long row = m0 + wm + mi * 16 + quad * 4 + r;
      float bm = BIAS_ROW ? bias[row] : 0.0f;
      for (int ni = 0; ni < 4; ni++) {
        float v = acc[mi][ni][r] + (BIAS_ROW ? bm : bv[ni]);
        long idx = row * (long)ldc + n0 + wn + ni * 16 + l16;
        if (OUT_F32) ((float*)Cout)[idx] = v;
        else         ((bf16*)Cout)[idx] = (bf16)v;
      }
    }
#undef STAGE_A
#undef STAGE_B
#undef READ_A
#undef READ_B
#undef MFMA16
#undef PHASE_MFMA
}

// ---------------- RoPE tables: ctab[pos][j] = {cos, sin}, j=0..63 ----------------
__global__ void ropetab_kernel(float* __restrict__ ctab) {
  int idx = blockIdx.x * 256 + threadIdx.x;   // 131072
  int j = idx & 63, p = idx >> 6;
  float f = exp2f(-(float)j * 0.20762050593046f);  // log2(10000)/64
  float th = (float)p * f;
  ctab[idx * 2]     = cosf(th);
  ctab[idx * 2 + 1] = sinf(th);
}

// ---------------- RoPE (NeoX rotate-half), in-place, table-driven ----------------
__global__ void rope_kernel(bf16* __restrict__ Q, bf16* __restrict__ K,
                            const float* __restrict__ ctab) {
  long idx = (long)blockIdx.x * 256 + threadIdx.x;   // 4194304 per tensor
  bf16* P = blockIdx.y ? K : Q;
  int i2 = (int)(idx & 31);          // dim pair (2*i2, 2*i2+1)
  int h  = (int)((idx >> 5) & 15);
  long row = idx >> 9;               // 0..8191
  int pos = (int)(row & (SEQ - 1));
  float4 cs = *(const float4*)(ctab + ((long)pos * 64 + 2 * i2) * 2); // c0,s0,c1,s1
  long base = row * D_MODEL + h * DK + 2 * i2;
  bf16x2 x1 = *(bf16x2*)(P + base);
  bf16x2 x2 = *(bf16x2*)(P + base + 64);
  bf16x2 y1, y2;
  y1[0] = (bf16)((float)x1[0] * cs.x - (float)x2[0] * cs.y);
  y2[0] = (bf16)((float)x2[0] * cs.x + (float)x1[0] * cs.y);
  y1[1] = (bf16)((float)x1[1] * cs.z - (float)x2[1] * cs.w);
  y2[1] = (bf16)((float)x2[1] * cs.z + (float)x1[1] * cs.w);
  *(bf16x2*)(P + base)      = y1;
  *(bf16x2*)(P + base + 64) = y2;
}

// ---------------- attention: O = softmax(Q K^T / sqrt(dk)) V ----------------
// (structure identical to R8/R9 + T1 chunked swizzle: XCD k gets bh in
// [8k, 8k+8) so concurrent blocks share K/V in L2. R9 measured FETCH 278 MB
// vs ~96 ideal -- K/V re-fetch from blocks sharing (b,h) being sprayed
// across XCDs.)
__global__ __launch_bounds__(256, 2)
void attn_kernel(const bf16* __restrict__ Q, const bf16* __restrict__ K,
                 const bf16* __restrict__ Vt, bf16* __restrict__ O)
{
  __shared__ alignas(16) bf16 Ks[2][64 * 128];   // [s][d] swizzled, 2 x 16 KB
  __shared__ alignas(16) bf16 Vts[2][128 * 64];  // [d][s] swizzled, 2 x 16 KB
  __shared__ alignas(16) bf16 Ps[128 * 36];      // half of P^T [q][s'=32 +pad4]
  const int tid  = threadIdx.x;
  const int wave = tid >> 6, lane = tid & 63;
  const int quad = lane >> 4, l16 = lane & 15;
  // T1 chunked swizzle (grid 16 x 64 = 1024 blocks; 1024 % 8 == 0, bijective)
  const int bid0 = blockIdx.y * 16 + blockIdx.x;
  const int lg = (bid0 & 7) * 128 + (bid0 >> 3);
  const int qt = lg & 15, bh = lg >> 4;
  const int b = bh >> 4, h = bh & 15;
  const long qrow0 = (long)b * SEQ + qt * 128;
  const bf16* Qb = Q + qrow0 * D_MODEL + h * DK;
  const bf16* Kb = K + (long)b * SEQ * D_MODEL + h * DK;
  const bf16* Vb = Vt + (long)(h * DK) * (BATCH * SEQ) + b * SEQ;  // ld = 8192

  bf16x8 Qf[2][4];
  for (int ni = 0; ni < 2; ni++)
    for (int ks = 0; ks < 4; ks++)
      Qf[ni][ks] = *(const bf16x8*)(Qb + (long)(wave * 32 + ni * 16 + l16) * D_MODEL + ks * 32 + quad * 8);

  const bf16* Ksrc[4]; const bf16* Vsrc[4];
  for (int i = 0; i < 4; i++) {
    int g = wave * 4 + i;
    int rk = 4 * g + (lane >> 4);                 // K tile row 0..63
    int ck = l16 ^ (rk & 7);
    Ksrc[i] = Kb + (long)rk * D_MODEL + ck * 8;
    int rv = 8 * g + (lane >> 3);                 // V tile row 0..127
    int cv = (lane & 7) ^ (rv & 7);
    Vsrc[i] = Vb + (long)rv * (BATCH * SEQ) + cv * 8;
  }

  f32x4 Oacc[8][2] = {};
  float lsum[2] = {0.0f, 0.0f};
  const float kSc = 0.088388347648318447f * 1.4426950408889634f; // (1/sqrt(128))*log2(e)
  const int swz = l16 & 7;

  for (int i = 0; i < 4; i++) gld_lds16(Ksrc[i], &Ks[0][(wave * 4 + i) * 512]);
  for (int i = 0; i < 4; i++) gld_lds16(Vsrc[i], &Vts[0][(wave * 4 + i) * 512]);
  __syncthreads();

  int cur = 0;
  for (int kt = 64; kt <= SEQ; kt += 64) {
    if (kt < SEQ) {
      for (int i = 0; i < 4; i++)
        gld_lds16(Ksrc[i] + (long)kt * D_MODEL, &Ks[cur ^ 1][(wave * 4 + i) * 512]);
      for (int i = 0; i < 4; i++)
        gld_lds16(Vsrc[i] + kt, &Vts[cur ^ 1][(wave * 4 + i) * 512]);
    }
    const bf16* Ksb = Ks[cur];
    const bf16* Vsb = Vts[cur];

    for (int hh = 0; hh < 2; hh++) {
      f32x4 Sc[2][2] = {};
      __builtin_amdgcn_s_setprio(1);
      for (int ks = 0; ks < 4; ks++) {
        bf16x8 Kf[2];
        for (int j = 0; j < 2; j++) {
          int si = hh * 2 + j;
          int c = (ks * 4 + quad) ^ swz;
          Kf[j] = *(const bf16x8*)(&Ksb[(si * 16 + l16) * 128 + c * 8]);
        }
        for (int j = 0; j < 2; j++)
          for (int ni = 0; ni < 2; ni++)
            Sc[j][ni] = __builtin_amdgcn_mfma_f32_16x16x32_bf16(Kf[j], Qf[ni][ks], Sc[j][ni], 0, 0, 0);
      }
      __builtin_amdgcn_s_setprio(0);

      for (int j = 0; j < 2; j++)
        for (int ni = 0; ni < 2; ni++) {
          bf16x4 pk;
          for (int r = 0; r < 4; r++) {
            float p = fast_exp2(Sc[j][ni][r] * kSc);
            lsum[ni] += p;
            pk[r] = (bf16)p;
          }
          *(bf16x4*)(&Ps[(wave * 32 + ni * 16 + l16) * 36 + j * 16 + quad * 4]) = pk;
        }

      __builtin_amdgcn_s_setprio(1);
      bf16x8 Pf[2];
      for (int ni = 0; ni < 2; ni++)
        Pf[ni] = *(const bf16x8*)(&Ps[(wave * 32 + ni * 16 + l16) * 36 + quad * 8]);
      for (int mi = 0; mi < 8; mi++) {
        int c = (hh * 4 + quad) ^ swz;
        bf16x8 Vf = *(const bf16x8*)(&Vsb[(mi * 16 + l16) * 64 + c * 8]);
        for (int ni = 0; ni < 2; ni++)
          Oacc[mi][ni] = __builtin_amdgcn_mfma_f32_16x16x32_bf16(Vf, Pf[ni], Oacc[mi][ni], 0, 0, 0);
      }
      __builtin_amdgcn_s_setprio(0);
    }

    __syncthreads();
    cur ^= 1;
  }

  for (int ni = 0; ni < 2; ni++) {
    lsum[ni] += __shfl_xor(lsum[ni], 16);
    lsum[ni] += __shfl_xor(lsum[ni], 32);
  }

  for (int ni = 0; ni < 2; ni++) {
    float rinv = 1.0f / lsum[ni];
    long rowbase = (qrow0 + wave * 32 + ni * 16 + l16) * (long)D_MODEL + h * DK + quad * 4;
    for (int mi = 0; mi < 8; mi++) {
      bf16x4 o;
      for (int r = 0; r < 4; r++) o[r] = (bf16)(Oacc[mi][ni][r] * rinv);
      *(bf16x4*)(O + rowbase + mi * 16) = o;
    }
  }
}

// ---------------- host ----------------
extern "C" void kernel_launch(void* const* d_in, const int* in_sizes, int n_in,
                              void* d_out, int out_size, void* d_ws, size_t ws_size,
                              hipStream_t stream) {
  const float* x  = (const float*)d_in[0];
  const float* Wq = (const float*)d_in[1];
  const float* bq = (const float*)d_in[2];
  const float* Wk = (const float*)d_in[3];
  const float* bk = (const float*)d_in[4];
  const float* Wv = (const float*)d_in[5];
  const float* bv = (const float*)d_in[6];
  const float* Wo = (const float*)d_in[7];
  const float* bo = (const float*)d_in[8];
  float* out = (float*)d_out;

  bf16* ws = (bf16*)d_ws;
  // bf16 element offsets; total 160 MB.
  bf16* xb  = ws;                    // 16777216 elems (dead after VtF gemm)
  bf16* Wqb = ws + 16777216;         //  4194304 each
  bf16* Wkb = ws + 20971520;
  bf16* Wvb = ws + 25165824;
  bf16* Wob = ws + 29360128;
  bf16* Qp  = ws + 33554432;         // 16777216
  bf16* Kp  = ws + 50331648;
  bf16* VtF = ws + 67108864;         // V^T: [2048 d^][8192 b*s]
  float* ctab = (float*)ws;          // 1 MB, alive only between VtF gemm and attn
  bf16* O   = xb;                    // attention output overlays xb (and ctab) after rope

  cvt_kernel<<<8192, 256, 0, stream>>>(x, xb, 2097152);
  cvt4_kernel<<<dim3(2048, 4), 256, 0, stream>>>(Wq, Wk, Wv, Wo, Wqb, Wkb, Wvb, Wob);

  // 256^2 tiles: grid = (N/256, M/256)
  gemm256<0, 0><<<dim3(8, 32), 512, 0, stream>>>(xb, Wqb, bq, Qp, 2048, 2048);
  gemm256<0, 0><<<dim3(8, 32), 512, 0, stream>>>(xb, Wkb, bk, Kp, 2048, 2048);
  // V^T = Wv · x^T : M=2048 (d^, row-bias bv), N=8192, ldc=8192
  gemm256<0, 1><<<dim3(32, 8), 512, 0, stream>>>(Wvb, xb, bv, VtF, 2048, 8192);

  ropetab_kernel<<<512, 256, 0, stream>>>(ctab);
  rope_kernel<<<dim3(16384, 2), 256, 0, stream>>>(Qp, Kp, ctab);

  attn_kernel<<<dim3(16, 64), 256, 0, stream>>>(Qp, Kp, VtF, O);

  gemm256<1, 0><<<dim3(8, 32), 512, 0, stream>>>(O, Wob, bo, out, 2048, 2048);
}